// Round 1
// baseline (4195.618 us; speedup 1.0000x reference)
//
#include <hip/hip_runtime.h>
#include <hip/hip_bf16.h>

#define T_TOKENS 2048
#define D_EMBD   1024
#define N_EXP    8
#define TOTAL_W  12288
#define TOPK     2

__device__ __constant__ int d_OFF[N_EXP] = {0,1024,2048,3072,4096,6144,8192,10240};
__device__ __constant__ int d_WID[N_EXP] = {1024,1024,1024,1024,2048,2048,2048,2048};

// -------- router: one block per token --------
__global__ __launch_bounds__(256) void router_kernel(
    const float* __restrict__ x, const float* __restrict__ rw,
    int* __restrict__ sel, float* __restrict__ wts)
{
    const int t   = blockIdx.x;
    const int tid = threadIdx.x;

    float acc[N_EXP];
#pragma unroll
    for (int e = 0; e < N_EXP; ++e) acc[e] = 0.f;

    const float* xt = x + (size_t)t * D_EMBD;
    for (int i = tid; i < D_EMBD; i += 256) {
        float xv = xt[i];
#pragma unroll
        for (int e = 0; e < N_EXP; ++e) acc[e] += xv * rw[e * D_EMBD + i];
    }
    // wave reduce (64 lanes)
#pragma unroll
    for (int e = 0; e < N_EXP; ++e)
#pragma unroll
        for (int o = 32; o > 0; o >>= 1) acc[e] += __shfl_down(acc[e], o, 64);

    __shared__ float red[4][N_EXP];
    const int wave = tid >> 6, lane = tid & 63;
    if (lane == 0)
#pragma unroll
        for (int e = 0; e < N_EXP; ++e) red[wave][e] = acc[e];
    __syncthreads();

    if (tid == 0) {
        float p[N_EXP];
#pragma unroll
        for (int e = 0; e < N_EXP; ++e) {
            float l = red[0][e] + red[1][e] + red[2][e] + red[3][e];
            p[e] = 1.f / (1.f + __expf(-l));
        }
        // top-1
        int e0 = 0;
#pragma unroll
        for (int e = 1; e < N_EXP; ++e) if (p[e] > p[e0]) e0 = e;
        // top-2 (first index on ties, excluding e0)
        int e1 = (e0 == 0) ? 1 : 0;
#pragma unroll
        for (int e = 0; e < N_EXP; ++e)
            if (e != e0 && p[e] > p[e1]) e1 = e;
        float w0 = p[e0], w1 = p[e1];
        float s = w0 + w1 + 1e-20f;
        sel[t * TOPK + 0] = e0;
        sel[t * TOPK + 1] = e1;
        wts[t * TOPK + 0] = w0 / s;
        wts[t * TOPK + 1] = w1 / s;
    }
}

// -------- expert MLP: one block per (token, k) assignment --------
template <int NU>  // columns-per-thread in up-proj (w/256): 4 or 8
__global__ __launch_bounds__(256) void moe_kernel(
    const float* __restrict__ x, const float* __restrict__ w1,
    const float* __restrict__ w2, const int* __restrict__ sel,
    const float* __restrict__ wts, float* __restrict__ out)
{
    const int a   = blockIdx.x;
    const int t   = a >> 1;
    const int k   = a & 1;
    const int tid = threadIdx.x;

    const int   e   = sel[t * TOPK + k];
    const float wgt = wts[t * TOPK + k];
    const int   off = d_OFF[e];
    const int   w   = d_WID[e];
    if (w != NU * 256) return;  // dispatched variant must match expert width

    __shared__ float xs[D_EMBD];
    __shared__ float hs[2048];

    const float* xt = x + (size_t)t * D_EMBD;
    for (int i = tid; i < D_EMBD; i += 256) xs[i] = xt[i];
    __syncthreads();

    // up-proj: thread handles columns j = tid + 256*u
    {
        float acc[NU];
#pragma unroll
        for (int u = 0; u < NU; ++u) acc[u] = 0.f;
        const float* base = w1 + off + tid;
        for (int i = 0; i < D_EMBD; ++i) {
            float xv = xs[i];
            const float* bi = base + (size_t)i * TOTAL_W;
#pragma unroll
            for (int u = 0; u < NU; ++u) acc[u] += xv * bi[u * 256];
        }
#pragma unroll
        for (int u = 0; u < NU; ++u) {
            float r = fmaxf(acc[u], 0.f);
            hs[tid + u * 256] = r * r;
        }
    }
    __syncthreads();

    // down-proj: thread handles output cols c = tid + 256*u (4 of them)
    {
        float acc[4];
#pragma unroll
        for (int u = 0; u < 4; ++u) acc[u] = 0.f;
        const float* base = w2 + (size_t)off * D_EMBD + tid;
        for (int j = 0; j < NU * 256; ++j) {
            float hv = hs[j];
            const float* bj = base + (size_t)j * D_EMBD;
#pragma unroll
            for (int u = 0; u < 4; ++u) acc[u] += hv * bj[u * 256];
        }
        float* ot = out + (size_t)t * D_EMBD + tid;
#pragma unroll
        for (int u = 0; u < 4; ++u)
            atomicAdd(&ot[u * 256], wgt * acc[u]);
    }
}

extern "C" void kernel_launch(void* const* d_in, const int* in_sizes, int n_in,
                              void* d_out, int out_size, void* d_ws, size_t ws_size,
                              hipStream_t stream) {
    const float* x  = (const float*)d_in[0];
    const float* rw = (const float*)d_in[1];
    const float* w1 = (const float*)d_in[2];
    const float* w2 = (const float*)d_in[3];
    float* out = (float*)d_out;

    int*   sel = (int*)d_ws;
    float* wts = (float*)((char*)d_ws + T_TOKENS * TOPK * sizeof(int));

    hipMemsetAsync(d_out, 0, (size_t)out_size * sizeof(float), stream);

    router_kernel<<<T_TOKENS, 256, 0, stream>>>(x, rw, sel, wts);

    // one block per (token, k); each block runs the variant matching its width
    moe_kernel<4><<<T_TOKENS * TOPK, 256, 0, stream>>>(x, w1, w2, sel, wts, out);
    moe_kernel<8><<<T_TOKENS * TOPK, 256, 0, stream>>>(x, w1, w2, sel, wts, out);
}

// Round 2
// 2481.521 us; speedup vs baseline: 1.6907x; 1.6907x over previous
//
#include <hip/hip_runtime.h>
#include <hip/hip_bf16.h>

#define T_TOKENS 2048
#define D_EMBD   1024
#define N_EXP    8
#define TOTAL_W  12288
#define TOPK     2
#define CAP      2048   // max tokens per expert (each token selects an expert at most once)

__device__ __constant__ int d_OFF[N_EXP] = {0,1024,2048,3072,4096,6144,8192,10240};
__device__ __constant__ int d_WID[N_EXP] = {1024,1024,1024,1024,2048,2048,2048,2048};

// -------- router + scatter: one block per token --------
__global__ __launch_bounds__(256) void router_kernel(
    const float* __restrict__ x, const float* __restrict__ rw,
    int* __restrict__ cnt, int* __restrict__ tok, float* __restrict__ wgtl)
{
    const int t   = blockIdx.x;
    const int tid = threadIdx.x;

    float acc[N_EXP];
#pragma unroll
    for (int e = 0; e < N_EXP; ++e) acc[e] = 0.f;

    const float* xt = x + (size_t)t * D_EMBD;
    for (int i = tid; i < D_EMBD; i += 256) {
        float xv = xt[i];
#pragma unroll
        for (int e = 0; e < N_EXP; ++e) acc[e] += xv * rw[e * D_EMBD + i];
    }
#pragma unroll
    for (int e = 0; e < N_EXP; ++e)
#pragma unroll
        for (int o = 32; o > 0; o >>= 1) acc[e] += __shfl_down(acc[e], o, 64);

    __shared__ float red[4][N_EXP];
    const int wave = tid >> 6, lane = tid & 63;
    if (lane == 0)
#pragma unroll
        for (int e = 0; e < N_EXP; ++e) red[wave][e] = acc[e];
    __syncthreads();

    if (tid == 0) {
        float p[N_EXP];
#pragma unroll
        for (int e = 0; e < N_EXP; ++e) {
            float l = red[0][e] + red[1][e] + red[2][e] + red[3][e];
            p[e] = 1.f / (1.f + __expf(-l));
        }
        int e0 = 0;
#pragma unroll
        for (int e = 1; e < N_EXP; ++e) if (p[e] > p[e0]) e0 = e;
        int e1 = (e0 == 0) ? 1 : 0;
#pragma unroll
        for (int e = 0; e < N_EXP; ++e)
            if (e != e0 && p[e] > p[e1]) e1 = e;
        float w0 = p[e0], w1 = p[e1];
        float s = w0 + w1 + 1e-20f;
        int s0 = atomicAdd(&cnt[e0], 1);
        tok[e0 * CAP + s0] = t;  wgtl[e0 * CAP + s0] = w0 / s;
        int s1 = atomicAdd(&cnt[e1], 1);
        tok[e1 * CAP + s1] = t;  wgtl[e1 * CAP + s1] = w1 / s;
    }
}

// -------- grouped expert MLP --------
// Block tile: 32 tokens x 4 width-tiles(128 each) x 512 out-cols.
// Thread tiles: up-proj (tg=tid>>5 -> 4 tokens, cg=tid&31 -> 4 w-cols),
//               down-proj (same tg -> 4 tokens, cg -> 16 out-cols as 4x float4).
__global__ __launch_bounds__(256, 3) void moe_group_kernel(
    const float* __restrict__ x, const float* __restrict__ w1,
    const float* __restrict__ w2, const int* __restrict__ cnt,
    const int* __restrict__ tok, const float* __restrict__ wgtl,
    float* __restrict__ out)
{
    // decode block -> (e, tt, colh, wh)
    int e, tt, colh, wh, nwh;
    int bx = blockIdx.x;
    if (bx < 1024) {             // narrow experts: 4 x (64tt x 2colh x 2wh)
        e = bx >> 8; int rem = bx & 255;
        wh = rem & 1; colh = (rem >> 1) & 1; tt = rem >> 2; nwh = 2;
    } else {                     // wide experts: 4 x (64tt x 2colh x 4wh)
        int b2 = bx - 1024;
        e = 4 + (b2 >> 9); int rem = b2 & 511;
        wh = rem & 3; colh = (rem >> 2) & 1; tt = rem >> 3; nwh = 4;
    }
    const int nt = cnt[e];
    if (tt * 32 >= nt) return;

    const int tid = threadIdx.x;
    const int off = d_OFF[e];
    const int wtn = d_WID[e] >> 7;          // width tiles total (8 or 16)
    const int wpb = wtn / nwh;              // width tiles per block (= 4)
    const int wt0 = wh * wpb;

    __shared__ float xs[128][36];
    __shared__ float hs[128][36];
    __shared__ int   ts_s[32];
    __shared__ float wg_s[32];

    if (tid < 32) {
        int s = tt * 32 + tid;
        ts_s[tid] = (s < nt) ? tok[e * CAP + s] : 0;
        wg_s[tid] = (s < nt) ? wgtl[e * CAP + s] : 0.f;
    }

    const int tg = tid >> 5;   // 0..7  (token group of 4)
    const int cg = tid & 31;   // 0..31

    float acc_dn[4][16];
#pragma unroll
    for (int a = 0; a < 4; ++a)
#pragma unroll
        for (int m = 0; m < 16; ++m) acc_dn[a][m] = 0.f;

    for (int wt = wt0; wt < wt0 + wpb; ++wt) {
        // ---- up-proj: h[32][128] for this width tile ----
        float au[4][4];
#pragma unroll
        for (int a = 0; a < 4; ++a)
#pragma unroll
            for (int b = 0; b < 4; ++b) au[a][b] = 0.f;

        const int cw1 = off + wt * 128 + cg * 4;
        for (int dc = 0; dc < 8; ++dc) {
            const int d0 = dc * 128;
            __syncthreads();
#pragma unroll
            for (int r = 0; r < 16; ++r) {
                int flat = r * 256 + tid;
                int ii = flat & 127, t = flat >> 7;
                xs[ii][t] = x[(size_t)ts_s[t] * D_EMBD + d0 + ii];
            }
            __syncthreads();

            const float* pw = w1 + (size_t)d0 * TOTAL_W + cw1;
            for (int ii = 0; ii < 128; ++ii) {
                const float4 xv = *reinterpret_cast<const float4*>(&xs[ii][tg * 4]);
                const float4 wv = *reinterpret_cast<const float4*>(pw);
                pw += TOTAL_W;
                const float xa[4] = {xv.x, xv.y, xv.z, xv.w};
                const float wb[4] = {wv.x, wv.y, wv.z, wv.w};
#pragma unroll
                for (int a = 0; a < 4; ++a)
#pragma unroll
                    for (int b = 0; b < 4; ++b) au[a][b] += xa[a] * wb[b];
            }
        }
        // relu^2 -> hs[c][t]
#pragma unroll
        for (int b = 0; b < 4; ++b) {
            float4 v;
            float r0 = fmaxf(au[0][b], 0.f), r1 = fmaxf(au[1][b], 0.f);
            float r2 = fmaxf(au[2][b], 0.f), r3 = fmaxf(au[3][b], 0.f);
            v.x = r0 * r0; v.y = r1 * r1; v.z = r2 * r2; v.w = r3 * r3;
            *reinterpret_cast<float4*>(&hs[cg * 4 + b][tg * 4]) = v;
        }
        __syncthreads();

        // ---- down-proj: accumulate out[32][512] over this width tile ----
        const float* pw2 = w2 + (size_t)(off + wt * 128) * D_EMBD + colh * 512 + cg * 4;
        for (int j = 0; j < 128; ++j) {
            const float4 hv = *reinterpret_cast<const float4*>(&hs[j][tg * 4]);
            const float ha[4] = {hv.x, hv.y, hv.z, hv.w};
            const float* row = pw2 + (size_t)j * D_EMBD;
#pragma unroll
            for (int b = 0; b < 4; ++b) {
                const float4 wv = *reinterpret_cast<const float4*>(row + b * 128);
                const float wq[4] = {wv.x, wv.y, wv.z, wv.w};
#pragma unroll
                for (int a = 0; a < 4; ++a)
#pragma unroll
                    for (int q = 0; q < 4; ++q)
                        acc_dn[a][b * 4 + q] += ha[a] * wq[q];
            }
        }
        __syncthreads();   // hs/xs reuse safety for next width tile
    }

    // ---- weighted atomic accumulate into out ----
#pragma unroll
    for (int a = 0; a < 4; ++a) {
        const int   t  = ts_s[tg * 4 + a];
        const float wg = wg_s[tg * 4 + a];
        float* ot = out + (size_t)t * D_EMBD + colh * 512 + cg * 4;
#pragma unroll
        for (int b = 0; b < 4; ++b)
#pragma unroll
            for (int q = 0; q < 4; ++q)
                atomicAdd(&ot[b * 128 + q], wg * acc_dn[a][b * 4 + q]);
    }
}

extern "C" void kernel_launch(void* const* d_in, const int* in_sizes, int n_in,
                              void* d_out, int out_size, void* d_ws, size_t ws_size,
                              hipStream_t stream) {
    const float* x  = (const float*)d_in[0];
    const float* rw = (const float*)d_in[1];
    const float* w1 = (const float*)d_in[2];
    const float* w2 = (const float*)d_in[3];
    float* out = (float*)d_out;

    int*   cnt  = (int*)d_ws;                                   // 8 ints (pad 64B)
    int*   tokl = (int*)((char*)d_ws + 64);                     // 8*2048 ints
    float* wgtl = (float*)((char*)d_ws + 64 + N_EXP * CAP * 4); // 8*2048 floats

    hipMemsetAsync(d_ws, 0, 64, stream);
    hipMemsetAsync(d_out, 0, (size_t)out_size * sizeof(float), stream);

    router_kernel<<<T_TOKENS, 256, 0, stream>>>(x, rw, cnt, tokl, wgtl);

    // narrow experts: 4*256 blocks; wide experts: 4*512 blocks
    moe_group_kernel<<<1024 + 2048, 256, 0, stream>>>(x, w1, w2, cnt, tokl, wgtl, out);
}

// Round 4
// 162.484 us; speedup vs baseline: 25.8218x; 15.2724x over previous
//
#include <hip/hip_runtime.h>
#include <hip/hip_bf16.h>

#define T_TOKENS 2048
#define D_EMBD   1024
#define N_EXP    8
#define TOTAL_W  12288
#define TOPK     2
#define CAP      2048
#define CAPH     2048

typedef __attribute__((ext_vector_type(8))) short bf16x8;
typedef __attribute__((ext_vector_type(4))) float f32x4;

__device__ __constant__ int d_OFF[N_EXP] = {0,1024,2048,3072,4096,6144,8192,10240};
__device__ __constant__ int d_WID[N_EXP] = {1024,1024,1024,1024,2048,2048,2048,2048};

// workspace layout (bytes)
#define WS_TOK   256
#define WS_WGT   (WS_TOK + N_EXP*CAP*4)
#define WS_XB    (WS_WGT + N_EXP*CAP*4)
#define WS_W1B   (WS_XB + T_TOKENS*D_EMBD*2)
#define WS_W2B   (WS_W1B + D_EMBD*TOTAL_W*2)
#define WS_H     (WS_W2B + (size_t)TOTAL_W*D_EMBD*2)
#define WS_END   (WS_H + (size_t)TOTAL_W*CAPH*2)

__device__ __forceinline__ void gload_lds16(const void* g, void* l) {
    __builtin_amdgcn_global_load_lds(
        (const __attribute__((address_space(1))) void*)g,
        (__attribute__((address_space(3))) void*)l, 16, 0, 0);
}

// -------- router + scatter (unchanged math) --------
__global__ __launch_bounds__(256) void router_kernel(
    const float* __restrict__ x, const float* __restrict__ rw,
    int* __restrict__ cnt, int* __restrict__ tok, float* __restrict__ wgtl)
{
    const int t   = blockIdx.x;
    const int tid = threadIdx.x;

    float acc[N_EXP];
#pragma unroll
    for (int e = 0; e < N_EXP; ++e) acc[e] = 0.f;

    const float* xt = x + (size_t)t * D_EMBD;
    for (int i = tid; i < D_EMBD; i += 256) {
        float xv = xt[i];
#pragma unroll
        for (int e = 0; e < N_EXP; ++e) acc[e] += xv * rw[e * D_EMBD + i];
    }
#pragma unroll
    for (int e = 0; e < N_EXP; ++e)
#pragma unroll
        for (int o = 32; o > 0; o >>= 1) acc[e] += __shfl_down(acc[e], o, 64);

    __shared__ float red[4][N_EXP];
    const int wave = tid >> 6, lane = tid & 63;
    if (lane == 0)
#pragma unroll
        for (int e = 0; e < N_EXP; ++e) red[wave][e] = acc[e];
    __syncthreads();

    if (tid == 0) {
        float p[N_EXP];
#pragma unroll
        for (int e = 0; e < N_EXP; ++e) {
            float l = red[0][e] + red[1][e] + red[2][e] + red[3][e];
            p[e] = 1.f / (1.f + __expf(-l));
        }
        int e0 = 0;
#pragma unroll
        for (int e = 1; e < N_EXP; ++e) if (p[e] > p[e0]) e0 = e;
        int e1 = (e0 == 0) ? 1 : 0;
#pragma unroll
        for (int e = 0; e < N_EXP; ++e)
            if (e != e0 && p[e] > p[e1]) e1 = e;
        float w0 = p[e0], w1 = p[e1];
        float s = w0 + w1 + 1e-20f;
        int s0 = atomicAdd(&cnt[e0], 1);
        tok[e0 * CAP + s0] = t;  wgtl[e0 * CAP + s0] = w0 / s;
        int s1 = atomicAdd(&cnt[e1], 1);
        tok[e1 * CAP + s1] = t;  wgtl[e1 * CAP + s1] = w1 / s;
    }
}

// -------- conversions --------
__global__ __launch_bounds__(256) void convx_kernel(
    const float* __restrict__ in, __hip_bfloat16* __restrict__ out)
{
    int i = blockIdx.x * 256 + threadIdx.x;          // 2048 blocks, 4 elems/thread
    const float4 v = reinterpret_cast<const float4*>(in)[i];
    __hip_bfloat16* o = out + (size_t)i * 4;
    o[0] = __float2bfloat16(v.x); o[1] = __float2bfloat16(v.y);
    o[2] = __float2bfloat16(v.z); o[3] = __float2bfloat16(v.w);
}

// out[c][r] = bf16(in[r][c]);  grid = (R/64)*(C/64)
__global__ __launch_bounds__(256) void transpose_bf16_kernel(
    const float* __restrict__ in, __hip_bfloat16* __restrict__ out, int R, int C)
{
    __shared__ float ls[64][65];
    const int nbc = C >> 6;
    const int br = blockIdx.x / nbc, bc = blockIdx.x % nbc;
    const int r0 = br << 6, c0 = bc << 6;
    const int tid = threadIdx.x;
#pragma unroll
    for (int i = 0; i < 16; ++i) {
        int flat = i * 256 + tid, r = flat >> 6, c = flat & 63;
        ls[r][c] = in[(size_t)(r0 + r) * C + c0 + c];
    }
    __syncthreads();
#pragma unroll
    for (int i = 0; i < 16; ++i) {
        int flat = i * 256 + tid, cc = flat >> 6, rr = flat & 63;
        out[(size_t)(c0 + cc) * R + r0 + rr] = __float2bfloat16(ls[rr][cc]);
    }
}

// -------- GEMM1: H[slot][w] = relu(X @ W1)^2  (bf16 out, fp32 acc) --------
// tile: 64 tokens x 128 width-cols x K64 steps; 4 waves, wave = 32x64 via 2x4 frags
__global__ __launch_bounds__(256) void gemm1_kernel(
    const char* __restrict__ xb, const char* __restrict__ w1b,
    const int* __restrict__ cnt, const int* __restrict__ tok,
    __hip_bfloat16* __restrict__ H)
{
    int bx = blockIdx.x, e, tt, nT;
    if (bx < 1024) { e = bx >> 8; int r = bx & 255; tt = r >> 3; nT = r & 7; }
    else { int b2 = bx - 1024; e = 4 + (b2 >> 9); int r = b2 & 511; tt = r >> 4; nT = r & 15; }
    const int nt = cnt[e];
    if (tt * 64 >= nt) return;

    const int we  = d_WID[e];
    const int n0  = nT * 128;
    const int tid = threadIdx.x;
    const int wv  = tid >> 6, lane = tid & 63;
    const int wr  = wv >> 1, wc = wv & 1;

    __shared__ __align__(16) char lds_buf[24576];   // A: [0,8K) 64x64 bf16; B: [8K,24K) 128x64 bf16
    __shared__ int ts_s[64];

    if (tid < 64) {
        int s = tt * 64 + tid;
        ts_s[tid] = (s < nt) ? tok[e * CAP + s] : 0;
    }
    __syncthreads();

    f32x4 acc[2][4];
#pragma unroll
    for (int mi = 0; mi < 2; ++mi)
#pragma unroll
        for (int nj = 0; nj < 4; ++nj) acc[mi][nj] = (f32x4){0.f,0.f,0.f,0.f};

    // FIX (R3): W1 columns for expert e start at global column d_OFF[e]; n0 is expert-local.
    const char* w1row = w1b + (size_t)(d_OFF[e] + n0) * 2048;  // w1b row stride 1024*2 B

    for (int ks = 0; ks < 16; ++ks) {
        const int k0b = ks * 128;                   // k-offset in bytes
        __syncthreads();
#pragma unroll
        for (int j = 0; j < 6; ++j) {
            const int ob = (wv * 6 + j) << 10;
            const int o  = ob + lane * 16;
            if (ob < 8192) {                        // A region: 64 rows x 128B
                int r = o >> 7, cb = o & 127;
                const char* src = xb + (size_t)ts_s[r] * 2048 + k0b + (cb ^ ((r & 7) << 4));
                gload_lds16(src, lds_buf + ob);
            } else {                                // B region: 128 rows x 128B
                int o2 = o - 8192, n = o2 >> 7, cb = o2 & 127;
                const char* src = w1row + (size_t)n * 2048 + k0b + (cb ^ ((n & 7) << 4));
                gload_lds16(src, lds_buf + ob);
            }
        }
        __syncthreads();

#pragma unroll
        for (int ksl = 0; ksl < 2; ++ksl) {
            const int kb = ksl * 64 + (lane >> 4) * 16;
            bf16x8 a[2], b[4];
#pragma unroll
            for (int mi = 0; mi < 2; ++mi) {
                int row = wr * 32 + mi * 16 + (lane & 15);
                a[mi] = *(const bf16x8*)(lds_buf + row * 128 + (kb ^ ((row & 7) << 4)));
            }
#pragma unroll
            for (int nj = 0; nj < 4; ++nj) {
                int n = wc * 64 + nj * 16 + (lane & 15);
                b[nj] = *(const bf16x8*)(lds_buf + 8192 + n * 128 + (kb ^ ((n & 7) << 4)));
            }
#pragma unroll
            for (int mi = 0; mi < 2; ++mi)
#pragma unroll
                for (int nj = 0; nj < 4; ++nj)
                    acc[mi][nj] = __builtin_amdgcn_mfma_f32_16x16x32_bf16(
                        a[mi], b[nj], acc[mi][nj], 0, 0, 0);
        }
    }

    // epilogue: relu^2 -> bf16 -> H[slot][we]
    const size_t hbase = (size_t)d_OFF[e] * CAPH;
#pragma unroll
    for (int mi = 0; mi < 2; ++mi)
#pragma unroll
        for (int q = 0; q < 4; ++q) {
            int row  = wr * 32 + mi * 16 + (lane >> 4) * 4 + q;
            int slot = tt * 64 + row;
            __hip_bfloat16* hp = H + hbase + (size_t)slot * we + n0 + wc * 64 + (lane & 15);
#pragma unroll
            for (int nj = 0; nj < 4; ++nj) {
                float v = fmaxf(acc[mi][nj][q], 0.f);
                hp[nj * 16] = __float2bfloat16(v * v);
            }
        }
}

// -------- GEMM2: out += wgt * (H @ W2)  --------
__global__ __launch_bounds__(256) void gemm2_kernel(
    const char* __restrict__ Hb, const char* __restrict__ w2b,
    const int* __restrict__ cnt, const int* __restrict__ tok,
    const float* __restrict__ wgtl, float* __restrict__ out)
{
    int bx = blockIdx.x;
    const int e  = bx >> 8;
    const int tt = (bx & 255) >> 3;
    const int nT = bx & 7;
    const int nt = cnt[e];
    if (tt * 64 >= nt) return;

    const int we  = d_WID[e];
    const int n0  = nT * 128;
    const int tid = threadIdx.x;
    const int wv  = tid >> 6, lane = tid & 63;
    const int wr  = wv >> 1, wc = wv & 1;

    __shared__ __align__(16) char lds_buf[24576];
    __shared__ int   ts_s[64];
    __shared__ float wg_s[64];

    if (tid < 64) {
        int s = tt * 64 + tid;
        ts_s[tid] = (s < nt) ? tok[e * CAP + s] : 0;
        wg_s[tid] = (s < nt) ? wgtl[e * CAP + s] : 0.f;
    }
    __syncthreads();

    f32x4 acc[2][4];
#pragma unroll
    for (int mi = 0; mi < 2; ++mi)
#pragma unroll
        for (int nj = 0; nj < 4; ++nj) acc[mi][nj] = (f32x4){0.f,0.f,0.f,0.f};

    const char*  Hbase  = Hb + (size_t)d_OFF[e] * CAPH * 2 + (size_t)tt * 64 * we * 2;
    const char*  w2row  = w2b + (size_t)n0 * (TOTAL_W * 2) + (size_t)d_OFF[e] * 2;
    const int    ksteps = we >> 6;

    for (int ks = 0; ks < ksteps; ++ks) {
        const int k0b = ks * 128;
        __syncthreads();
#pragma unroll
        for (int j = 0; j < 6; ++j) {
            const int ob = (wv * 6 + j) << 10;
            const int o  = ob + lane * 16;
            if (ob < 8192) {
                int r = o >> 7, cb = o & 127;
                const char* src = Hbase + (size_t)r * (we * 2) + k0b + (cb ^ ((r & 7) << 4));
                gload_lds16(src, lds_buf + ob);
            } else {
                int o2 = o - 8192, n = o2 >> 7, cb = o2 & 127;
                const char* src = w2row + (size_t)n * (TOTAL_W * 2) + k0b + (cb ^ ((n & 7) << 4));
                gload_lds16(src, lds_buf + ob);
            }
        }
        __syncthreads();

#pragma unroll
        for (int ksl = 0; ksl < 2; ++ksl) {
            const int kb = ksl * 64 + (lane >> 4) * 16;
            bf16x8 a[2], b[4];
#pragma unroll
            for (int mi = 0; mi < 2; ++mi) {
                int row = wr * 32 + mi * 16 + (lane & 15);
                a[mi] = *(const bf16x8*)(lds_buf + row * 128 + (kb ^ ((row & 7) << 4)));
            }
#pragma unroll
            for (int nj = 0; nj < 4; ++nj) {
                int n = wc * 64 + nj * 16 + (lane & 15);
                b[nj] = *(const bf16x8*)(lds_buf + 8192 + n * 128 + (kb ^ ((n & 7) << 4)));
            }
#pragma unroll
            for (int mi = 0; mi < 2; ++mi)
#pragma unroll
                for (int nj = 0; nj < 4; ++nj)
                    acc[mi][nj] = __builtin_amdgcn_mfma_f32_16x16x32_bf16(
                        a[mi], b[nj], acc[mi][nj], 0, 0, 0);
        }
    }

#pragma unroll
    for (int mi = 0; mi < 2; ++mi)
#pragma unroll
        for (int q = 0; q < 4; ++q) {
            int row  = wr * 32 + mi * 16 + (lane >> 4) * 4 + q;
            int slot = tt * 64 + row;
            if (slot < nt) {
                const int   t  = ts_s[row];
                const float wg = wg_s[row];
                float* op = out + (size_t)t * D_EMBD + n0 + wc * 64 + (lane & 15);
#pragma unroll
                for (int nj = 0; nj < 4; ++nj)
                    atomicAdd(&op[nj * 16], wg * acc[mi][nj][q]);
            }
        }
}

// -------- round-2 fp32 fallback (if ws too small) --------
__global__ __launch_bounds__(256, 3) void moe_group_kernel(
    const float* __restrict__ x, const float* __restrict__ w1,
    const float* __restrict__ w2, const int* __restrict__ cnt,
    const int* __restrict__ tok, const float* __restrict__ wgtl,
    float* __restrict__ out)
{
    int e, tt, colh, wh, nwh;
    int bx = blockIdx.x;
    if (bx < 1024) { e = bx >> 8; int rem = bx & 255; wh = rem & 1; colh = (rem >> 1) & 1; tt = rem >> 2; nwh = 2; }
    else { int b2 = bx - 1024; e = 4 + (b2 >> 9); int rem = b2 & 511; wh = rem & 3; colh = (rem >> 2) & 1; tt = rem >> 3; nwh = 4; }
    const int nt = cnt[e];
    if (tt * 32 >= nt) return;

    const int tid = threadIdx.x;
    const int off = d_OFF[e];
    const int wtn = d_WID[e] >> 7;
    const int wpb = wtn / nwh;
    const int wt0 = wh * wpb;

    __shared__ float xs[128][36];
    __shared__ float hs[128][36];
    __shared__ int   ts_s[32];
    __shared__ float wg_s[32];

    if (tid < 32) {
        int s = tt * 32 + tid;
        ts_s[tid] = (s < nt) ? tok[e * CAP + s] : 0;
        wg_s[tid] = (s < nt) ? wgtl[e * CAP + s] : 0.f;
    }

    const int tg = tid >> 5, cg = tid & 31;
    float acc_dn[4][16];
#pragma unroll
    for (int a = 0; a < 4; ++a)
#pragma unroll
        for (int m = 0; m < 16; ++m) acc_dn[a][m] = 0.f;

    for (int wt = wt0; wt < wt0 + wpb; ++wt) {
        float au[4][4];
#pragma unroll
        for (int a = 0; a < 4; ++a)
#pragma unroll
            for (int b = 0; b < 4; ++b) au[a][b] = 0.f;
        const int cw1 = off + wt * 128 + cg * 4;
        for (int dc = 0; dc < 8; ++dc) {
            const int d0 = dc * 128;
            __syncthreads();
#pragma unroll
            for (int r = 0; r < 16; ++r) {
                int flat = r * 256 + tid, ii = flat & 127, t = flat >> 7;
                xs[ii][t] = x[(size_t)ts_s[t] * D_EMBD + d0 + ii];
            }
            __syncthreads();
            const float* pw = w1 + (size_t)d0 * TOTAL_W + cw1;
            for (int ii = 0; ii < 128; ++ii) {
                const float4 xv = *reinterpret_cast<const float4*>(&xs[ii][tg * 4]);
                const float4 wv = *reinterpret_cast<const float4*>(pw);
                pw += TOTAL_W;
                const float xa[4] = {xv.x, xv.y, xv.z, xv.w};
                const float wb[4] = {wv.x, wv.y, wv.z, wv.w};
#pragma unroll
                for (int a = 0; a < 4; ++a)
#pragma unroll
                    for (int b = 0; b < 4; ++b) au[a][b] += xa[a] * wb[b];
            }
        }
#pragma unroll
        for (int b = 0; b < 4; ++b) {
            float4 v;
            float r0 = fmaxf(au[0][b], 0.f), r1 = fmaxf(au[1][b], 0.f);
            float r2 = fmaxf(au[2][b], 0.f), r3 = fmaxf(au[3][b], 0.f);
            v.x = r0 * r0; v.y = r1 * r1; v.z = r2 * r2; v.w = r3 * r3;
            *reinterpret_cast<float4*>(&hs[cg * 4 + b][tg * 4]) = v;
        }
        __syncthreads();
        const float* pw2 = w2 + (size_t)(off + wt * 128) * D_EMBD + colh * 512 + cg * 4;
        for (int j = 0; j < 128; ++j) {
            const float4 hv = *reinterpret_cast<const float4*>(&hs[j][tg * 4]);
            const float ha[4] = {hv.x, hv.y, hv.z, hv.w};
            const float* row = pw2 + (size_t)j * D_EMBD;
#pragma unroll
            for (int b = 0; b < 4; ++b) {
                const float4 wv = *reinterpret_cast<const float4*>(row + b * 128);
                const float wq[4] = {wv.x, wv.y, wv.z, wv.w};
#pragma unroll
                for (int a = 0; a < 4; ++a)
#pragma unroll
                    for (int q = 0; q < 4; ++q)
                        acc_dn[a][b * 4 + q] += ha[a] * wq[q];
            }
        }
        __syncthreads();
    }
#pragma unroll
    for (int a = 0; a < 4; ++a) {
        const int   t  = ts_s[tg * 4 + a];
        const float wg = wg_s[tg * 4 + a];
        float* ot = out + (size_t)t * D_EMBD + colh * 512 + cg * 4;
#pragma unroll
        for (int b = 0; b < 4; ++b)
#pragma unroll
            for (int q = 0; q < 4; ++q)
                atomicAdd(&ot[b * 128 + q], wg * acc_dn[a][b * 4 + q]);
    }
}

extern "C" void kernel_launch(void* const* d_in, const int* in_sizes, int n_in,
                              void* d_out, int out_size, void* d_ws, size_t ws_size,
                              hipStream_t stream) {
    const float* x  = (const float*)d_in[0];
    const float* rw = (const float*)d_in[1];
    const float* w1 = (const float*)d_in[2];
    const float* w2 = (const float*)d_in[3];
    float* out = (float*)d_out;

    char* ws = (char*)d_ws;
    int*   cnt  = (int*)ws;
    int*   tokl = (int*)(ws + WS_TOK);
    float* wgtl = (float*)(ws + WS_WGT);

    hipMemsetAsync(d_ws, 0, 64, stream);
    hipMemsetAsync(d_out, 0, (size_t)out_size * sizeof(float), stream);

    router_kernel<<<T_TOKENS, 256, 0, stream>>>(x, rw, cnt, tokl, wgtl);

    if (ws_size >= WS_END) {
        __hip_bfloat16* xb  = (__hip_bfloat16*)(ws + WS_XB);
        __hip_bfloat16* w1b = (__hip_bfloat16*)(ws + WS_W1B);
        __hip_bfloat16* w2b = (__hip_bfloat16*)(ws + WS_W2B);
        __hip_bfloat16* H   = (__hip_bfloat16*)(ws + WS_H);

        convx_kernel<<<T_TOKENS * D_EMBD / 1024, 256, 0, stream>>>(x, xb);
        transpose_bf16_kernel<<<(D_EMBD/64)*(TOTAL_W/64), 256, 0, stream>>>(w1, w1b, D_EMBD, TOTAL_W);
        transpose_bf16_kernel<<<(TOTAL_W/64)*(D_EMBD/64), 256, 0, stream>>>(w2, w2b, TOTAL_W, D_EMBD);

        gemm1_kernel<<<3072, 256, 0, stream>>>((const char*)xb, (const char*)w1b, cnt, tokl, H);
        gemm2_kernel<<<2048, 256, 0, stream>>>((const char*)H, (const char*)w2b, cnt, tokl, wgtl, out);
    } else {
        moe_group_kernel<<<1024 + 2048, 256, 0, stream>>>(x, w1, w2, cnt, tokl, wgtl, out);
    }
}

// Round 5
// 137.104 us; speedup vs baseline: 30.6016x; 1.1851x over previous
//
#include <hip/hip_runtime.h>
#include <hip/hip_bf16.h>

#define T_TOKENS 2048
#define D_EMBD   1024
#define N_EXP    8
#define TOTAL_W  12288
#define TOPK     2
#define CAP      2048
#define CAPH     2048

typedef __attribute__((ext_vector_type(8))) short bf16x8;
typedef __attribute__((ext_vector_type(4))) float f32x4;
typedef __attribute__((ext_vector_type(4))) unsigned short u16x4;

__device__ __constant__ int d_OFF[N_EXP] = {0,1024,2048,3072,4096,6144,8192,10240};
__device__ __constant__ int d_WID[N_EXP] = {1024,1024,1024,1024,2048,2048,2048,2048};

// workspace layout (bytes). cnt: 8 counters padded to 128B stride (atomic contention fix).
#define WS_TOK   1024
#define WS_WGT   (WS_TOK + N_EXP*CAP*4)
#define WS_XB    (WS_WGT + N_EXP*CAP*4)
#define WS_W1B   (WS_XB + T_TOKENS*D_EMBD*2)
#define WS_W2B   (WS_W1B + D_EMBD*TOTAL_W*2)
#define WS_H     (WS_W2B + (size_t)TOTAL_W*D_EMBD*2)
#define WS_END   (WS_H + (size_t)TOTAL_W*CAPH*2)

__device__ __forceinline__ void gload_lds16(const void* g, void* l) {
    __builtin_amdgcn_global_load_lds(
        (const __attribute__((address_space(1))) void*)g,
        (__attribute__((address_space(3))) void*)l, 16, 0, 0);
}

__device__ __forceinline__ unsigned short f2bf(float f) {
    __hip_bfloat16 h = __float2bfloat16(f);
    return *reinterpret_cast<unsigned short*>(&h);
}

// -------- router v2: 64 blocks x 32 tokens; LDS bucketing, padded global atomics --------
__global__ __launch_bounds__(256) void router2_kernel(
    const float* __restrict__ x, const float* __restrict__ rw,
    int* __restrict__ cnt, int* __restrict__ tok, float* __restrict__ wgtl)
{
    const int tid = threadIdx.x, wv = tid >> 6, lane = tid & 63;
    __shared__ float rws[N_EXP * 1024];
    __shared__ int   lcnt[N_EXP];
    __shared__ int   lbase[N_EXP];
    __shared__ int   ltok[N_EXP][32];
    __shared__ float lwgt[N_EXP][32];

    {   // stage router weights (32KB) in LDS
        const float4* src = (const float4*)rw;
        float4* dst = (float4*)rws;
        for (int i = tid; i < N_EXP * 256; i += 256) dst[i] = src[i];
    }
    if (tid < N_EXP) lcnt[tid] = 0;
    __syncthreads();

    const float4* x4 = (const float4*)x;
    for (int ts = 0; ts < 8; ++ts) {
        const int t = blockIdx.x * 32 + wv * 8 + ts;
        float4 xv[4];
#pragma unroll
        for (int i = 0; i < 4; ++i) xv[i] = x4[(size_t)t * 256 + lane + 64 * i];
        float acc[N_EXP];
#pragma unroll
        for (int e = 0; e < N_EXP; ++e) {
            float a = 0.f;
#pragma unroll
            for (int i = 0; i < 4; ++i) {
                float4 w4 = ((const float4*)(rws + e * 1024))[lane + 64 * i];
                a += xv[i].x * w4.x + xv[i].y * w4.y + xv[i].z * w4.z + xv[i].w * w4.w;
            }
            acc[e] = a;
        }
#pragma unroll
        for (int e = 0; e < N_EXP; ++e)
#pragma unroll
            for (int o = 32; o > 0; o >>= 1) acc[e] += __shfl_xor(acc[e], o, 64);

        if (lane == 0) {
            float p[N_EXP];
#pragma unroll
            for (int e = 0; e < N_EXP; ++e) p[e] = 1.f / (1.f + __expf(-acc[e]));
            int e0 = 0;
#pragma unroll
            for (int e = 1; e < N_EXP; ++e) if (p[e] > p[e0]) e0 = e;
            int e1 = (e0 == 0) ? 1 : 0;
#pragma unroll
            for (int e = 0; e < N_EXP; ++e) if (e != e0 && p[e] > p[e1]) e1 = e;
            float w0 = p[e0], w1 = p[e1], s = w0 + w1 + 1e-20f;
            int s0 = atomicAdd(&lcnt[e0], 1);
            ltok[e0][s0] = t;  lwgt[e0][s0] = w0 / s;
            int s1 = atomicAdd(&lcnt[e1], 1);
            ltok[e1][s1] = t;  lwgt[e1][s1] = w1 / s;
        }
    }
    __syncthreads();
    if (tid < N_EXP) lbase[tid] = atomicAdd(&cnt[tid << 5], lcnt[tid]);
    __syncthreads();
    {
        const int e = tid >> 5, i = tid & 31;
        if (i < lcnt[e]) {
            int dst = e * CAP + lbase[e] + i;
            tok[dst]  = ltok[e][i];
            wgtl[dst] = lwgt[e][i];
        }
    }
}

// -------- conversions --------
__global__ __launch_bounds__(256) void convx_kernel(
    const float* __restrict__ in, __hip_bfloat16* __restrict__ out)
{
    int i = blockIdx.x * 256 + threadIdx.x;          // 2048 blocks, 4 elems/thread
    const float4 v = reinterpret_cast<const float4*>(in)[i];
    u16x4 o;
    o[0] = f2bf(v.x); o[1] = f2bf(v.y); o[2] = f2bf(v.z); o[3] = f2bf(v.w);
    *reinterpret_cast<u16x4*>(out + (size_t)i * 4) = o;
}

// out[c][r] = bf16(in[r][c]);  grid = (R/64)*(C/64)
__global__ __launch_bounds__(256) void transpose_bf16_kernel(
    const float* __restrict__ in, __hip_bfloat16* __restrict__ out, int R, int C)
{
    __shared__ float ls[64][65];
    const int nbc = C >> 6;
    const int br = blockIdx.x / nbc, bc = blockIdx.x % nbc;
    const int r0 = br << 6, c0 = bc << 6;
    const int tid = threadIdx.x;
#pragma unroll
    for (int i = 0; i < 4; ++i) {
        int flat = i * 1024 + tid * 4;
        int r = flat >> 6, c = flat & 63;
        float4 v = *reinterpret_cast<const float4*>(&in[(size_t)(r0 + r) * C + c0 + c]);
        ls[r][c] = v.x; ls[r][c + 1] = v.y; ls[r][c + 2] = v.z; ls[r][c + 3] = v.w;
    }
    __syncthreads();
#pragma unroll
    for (int i = 0; i < 4; ++i) {
        int flat = i * 1024 + tid * 4;
        int cc = flat >> 6, rr = flat & 63;
        u16x4 o;
        o[0] = f2bf(ls[rr + 0][cc]); o[1] = f2bf(ls[rr + 1][cc]);
        o[2] = f2bf(ls[rr + 2][cc]); o[3] = f2bf(ls[rr + 3][cc]);
        *reinterpret_cast<u16x4*>(&out[(size_t)(c0 + cc) * R + r0 + rr]) = o;
    }
}

// -------- GEMM1: H[slot][w] = relu(X @ W1)^2  (bf16 out, fp32 acc) --------
// tile: 64 tokens x 128 width-cols x K64 steps; 4 waves, wave = 32x64 via 2x4 frags
__global__ __launch_bounds__(256) void gemm1_kernel(
    const char* __restrict__ xb, const char* __restrict__ w1b,
    const int* __restrict__ cnt, const int* __restrict__ tok,
    __hip_bfloat16* __restrict__ H)
{
    int bx = blockIdx.x, e, tt, nT;
    if (bx < 1024) { e = bx >> 8; int r = bx & 255; tt = r >> 3; nT = r & 7; }
    else { int b2 = bx - 1024; e = 4 + (b2 >> 9); int r = b2 & 511; tt = r >> 4; nT = r & 15; }
    const int nt = cnt[e << 5];
    if (tt * 64 >= nt) return;

    const int we  = d_WID[e];
    const int n0  = nT * 128;
    const int tid = threadIdx.x;
    const int wv  = tid >> 6, lane = tid & 63;
    const int wr  = wv >> 1, wc = wv & 1;

    __shared__ __align__(16) char lds_buf[24576];   // A: [0,8K) 64x64 bf16; B: [8K,24K) 128x64 bf16
    __shared__ int ts_s[64];

    if (tid < 64) {
        int s = tt * 64 + tid;
        ts_s[tid] = (s < nt) ? tok[e * CAP + s] : 0;
    }
    __syncthreads();

    f32x4 acc[2][4];
#pragma unroll
    for (int mi = 0; mi < 2; ++mi)
#pragma unroll
        for (int nj = 0; nj < 4; ++nj) acc[mi][nj] = (f32x4){0.f,0.f,0.f,0.f};

    const char* w1row = w1b + (size_t)(d_OFF[e] + n0) * 2048;  // w1b row stride 1024*2 B

    for (int ks = 0; ks < 16; ++ks) {
        const int k0b = ks * 128;                   // k-offset in bytes
        __syncthreads();
#pragma unroll
        for (int j = 0; j < 6; ++j) {
            const int ob = (wv * 6 + j) << 10;
            const int o  = ob + lane * 16;
            if (ob < 8192) {                        // A region: 64 rows x 128B
                int r = o >> 7, cb = o & 127;
                const char* src = xb + (size_t)ts_s[r] * 2048 + k0b + (cb ^ ((r & 7) << 4));
                gload_lds16(src, lds_buf + ob);
            } else {                                // B region: 128 rows x 128B
                int o2 = o - 8192, n = o2 >> 7, cb = o2 & 127;
                const char* src = w1row + (size_t)n * 2048 + k0b + (cb ^ ((n & 7) << 4));
                gload_lds16(src, lds_buf + ob);
            }
        }
        __syncthreads();

#pragma unroll
        for (int ksl = 0; ksl < 2; ++ksl) {
            const int kb = ksl * 64 + (lane >> 4) * 16;
            bf16x8 a[2], b[4];
#pragma unroll
            for (int mi = 0; mi < 2; ++mi) {
                int row = wr * 32 + mi * 16 + (lane & 15);
                a[mi] = *(const bf16x8*)(lds_buf + row * 128 + (kb ^ ((row & 7) << 4)));
            }
#pragma unroll
            for (int nj = 0; nj < 4; ++nj) {
                int n = wc * 64 + nj * 16 + (lane & 15);
                b[nj] = *(const bf16x8*)(lds_buf + 8192 + n * 128 + (kb ^ ((n & 7) << 4)));
            }
#pragma unroll
            for (int mi = 0; mi < 2; ++mi)
#pragma unroll
                for (int nj = 0; nj < 4; ++nj)
                    acc[mi][nj] = __builtin_amdgcn_mfma_f32_16x16x32_bf16(
                        a[mi], b[nj], acc[mi][nj], 0, 0, 0);
        }
    }

    // epilogue: relu^2 -> bf16 -> H[slot][we]
    const size_t hbase = (size_t)d_OFF[e] * CAPH;
#pragma unroll
    for (int mi = 0; mi < 2; ++mi)
#pragma unroll
        for (int q = 0; q < 4; ++q) {
            int row  = wr * 32 + mi * 16 + (lane >> 4) * 4 + q;
            int slot = tt * 64 + row;
            __hip_bfloat16* hp = H + hbase + (size_t)slot * we + n0 + wc * 64 + (lane & 15);
#pragma unroll
            for (int nj = 0; nj < 4; ++nj) {
                float v = fmaxf(acc[mi][nj][q], 0.f);
                hp[nj * 16] = __float2bfloat16(v * v);
            }
        }
}

// -------- GEMM2: out += wgt * (H @ W2)  --------
__global__ __launch_bounds__(256) void gemm2_kernel(
    const char* __restrict__ Hb, const char* __restrict__ w2b,
    const int* __restrict__ cnt, const int* __restrict__ tok,
    const float* __restrict__ wgtl, float* __restrict__ out)
{
    int bx = blockIdx.x;
    const int e  = bx >> 8;
    const int tt = (bx & 255) >> 3;
    const int nT = bx & 7;
    const int nt = cnt[e << 5];
    if (tt * 64 >= nt) return;

    const int we  = d_WID[e];
    const int n0  = nT * 128;
    const int tid = threadIdx.x;
    const int wv  = tid >> 6, lane = tid & 63;
    const int wr  = wv >> 1, wc = wv & 1;

    __shared__ __align__(16) char lds_buf[24576];
    __shared__ int   ts_s[64];
    __shared__ float wg_s[64];

    if (tid < 64) {
        int s = tt * 64 + tid;
        ts_s[tid] = (s < nt) ? tok[e * CAP + s] : 0;
        wg_s[tid] = (s < nt) ? wgtl[e * CAP + s] : 0.f;
    }
    __syncthreads();

    f32x4 acc[2][4];
#pragma unroll
    for (int mi = 0; mi < 2; ++mi)
#pragma unroll
        for (int nj = 0; nj < 4; ++nj) acc[mi][nj] = (f32x4){0.f,0.f,0.f,0.f};

    const char*  Hbase  = Hb + (size_t)d_OFF[e] * CAPH * 2 + (size_t)tt * 64 * we * 2;
    const char*  w2row  = w2b + (size_t)n0 * (TOTAL_W * 2) + (size_t)d_OFF[e] * 2;
    const int    ksteps = we >> 6;

    for (int ks = 0; ks < ksteps; ++ks) {
        const int k0b = ks * 128;
        __syncthreads();
#pragma unroll
        for (int j = 0; j < 6; ++j) {
            const int ob = (wv * 6 + j) << 10;
            const int o  = ob + lane * 16;
            if (ob < 8192) {
                int r = o >> 7, cb = o & 127;
                const char* src = Hbase + (size_t)r * (we * 2) + k0b + (cb ^ ((r & 7) << 4));
                gload_lds16(src, lds_buf + ob);
            } else {
                int o2 = o - 8192, n = o2 >> 7, cb = o2 & 127;
                const char* src = w2row + (size_t)n * (TOTAL_W * 2) + k0b + (cb ^ ((n & 7) << 4));
                gload_lds16(src, lds_buf + ob);
            }
        }
        __syncthreads();

#pragma unroll
        for (int ksl = 0; ksl < 2; ++ksl) {
            const int kb = ksl * 64 + (lane >> 4) * 16;
            bf16x8 a[2], b[4];
#pragma unroll
            for (int mi = 0; mi < 2; ++mi) {
                int row = wr * 32 + mi * 16 + (lane & 15);
                a[mi] = *(const bf16x8*)(lds_buf + row * 128 + (kb ^ ((row & 7) << 4)));
            }
#pragma unroll
            for (int nj = 0; nj < 4; ++nj) {
                int n = wc * 64 + nj * 16 + (lane & 15);
                b[nj] = *(const bf16x8*)(lds_buf + 8192 + n * 128 + (kb ^ ((n & 7) << 4)));
            }
#pragma unroll
            for (int mi = 0; mi < 2; ++mi)
#pragma unroll
                for (int nj = 0; nj < 4; ++nj)
                    acc[mi][nj] = __builtin_amdgcn_mfma_f32_16x16x32_bf16(
                        a[mi], b[nj], acc[mi][nj], 0, 0, 0);
        }
    }

#pragma unroll
    for (int mi = 0; mi < 2; ++mi)
#pragma unroll
        for (int q = 0; q < 4; ++q) {
            int row  = wr * 32 + mi * 16 + (lane >> 4) * 4 + q;
            int slot = tt * 64 + row;
            if (slot < nt) {
                const int   t  = ts_s[row];
                const float wg = wg_s[row];
                float* op = out + (size_t)t * D_EMBD + n0 + wc * 64 + (lane & 15);
#pragma unroll
                for (int nj = 0; nj < 4; ++nj)
                    atomicAdd(&op[nj * 16], wg * acc[mi][nj][q]);
            }
        }
}

// -------- round-2 fp32 fallback (if ws too small) --------
__global__ __launch_bounds__(256, 3) void moe_group_kernel(
    const float* __restrict__ x, const float* __restrict__ w1,
    const float* __restrict__ w2, const int* __restrict__ cnt,
    const int* __restrict__ tok, const float* __restrict__ wgtl,
    float* __restrict__ out)
{
    int e, tt, colh, wh, nwh;
    int bx = blockIdx.x;
    if (bx < 1024) { e = bx >> 8; int rem = bx & 255; wh = rem & 1; colh = (rem >> 1) & 1; tt = rem >> 2; nwh = 2; }
    else { int b2 = bx - 1024; e = 4 + (b2 >> 9); int rem = b2 & 511; wh = rem & 3; colh = (rem >> 2) & 1; tt = rem >> 3; nwh = 4; }
    const int nt = cnt[e << 5];
    if (tt * 32 >= nt) return;

    const int tid = threadIdx.x;
    const int off = d_OFF[e];
    const int wtn = d_WID[e] >> 7;
    const int wpb = wtn / nwh;
    const int wt0 = wh * wpb;

    __shared__ float xs[128][36];
    __shared__ float hs[128][36];
    __shared__ int   ts_s[32];
    __shared__ float wg_s[32];

    if (tid < 32) {
        int s = tt * 32 + tid;
        ts_s[tid] = (s < nt) ? tok[e * CAP + s] : 0;
        wg_s[tid] = (s < nt) ? wgtl[e * CAP + s] : 0.f;
    }

    const int tg = tid >> 5, cg = tid & 31;
    float acc_dn[4][16];
#pragma unroll
    for (int a = 0; a < 4; ++a)
#pragma unroll
        for (int m = 0; m < 16; ++m) acc_dn[a][m] = 0.f;

    for (int wt = wt0; wt < wt0 + wpb; ++wt) {
        float au[4][4];
#pragma unroll
        for (int a = 0; a < 4; ++a)
#pragma unroll
            for (int b = 0; b < 4; ++b) au[a][b] = 0.f;
        const int cw1 = off + wt * 128 + cg * 4;
        for (int dc = 0; dc < 8; ++dc) {
            const int d0 = dc * 128;
            __syncthreads();
#pragma unroll
            for (int r = 0; r < 16; ++r) {
                int flat = r * 256 + tid, ii = flat & 127, t = flat >> 7;
                xs[ii][t] = x[(size_t)ts_s[t] * D_EMBD + d0 + ii];
            }
            __syncthreads();
            const float* pw = w1 + (size_t)d0 * TOTAL_W + cw1;
            for (int ii = 0; ii < 128; ++ii) {
                const float4 xv = *reinterpret_cast<const float4*>(&xs[ii][tg * 4]);
                const float4 wv = *reinterpret_cast<const float4*>(pw);
                pw += TOTAL_W;
                const float xa[4] = {xv.x, xv.y, xv.z, xv.w};
                const float wb[4] = {wv.x, wv.y, wv.z, wv.w};
#pragma unroll
                for (int a = 0; a < 4; ++a)
#pragma unroll
                    for (int b = 0; b < 4; ++b) au[a][b] += xa[a] * wb[b];
            }
        }
#pragma unroll
        for (int b = 0; b < 4; ++b) {
            float4 v;
            float r0 = fmaxf(au[0][b], 0.f), r1 = fmaxf(au[1][b], 0.f);
            float r2 = fmaxf(au[2][b], 0.f), r3 = fmaxf(au[3][b], 0.f);
            v.x = r0 * r0; v.y = r1 * r1; v.z = r2 * r2; v.w = r3 * r3;
            *reinterpret_cast<float4*>(&hs[cg * 4 + b][tg * 4]) = v;
        }
        __syncthreads();
        const float* pw2 = w2 + (size_t)(off + wt * 128) * D_EMBD + colh * 512 + cg * 4;
        for (int j = 0; j < 128; ++j) {
            const float4 hv = *reinterpret_cast<const float4*>(&hs[j][tg * 4]);
            const float ha[4] = {hv.x, hv.y, hv.z, hv.w};
            const float* row = pw2 + (size_t)j * D_EMBD;
#pragma unroll
            for (int b = 0; b < 4; ++b) {
                const float4 wv = *reinterpret_cast<const float4*>(row + b * 128);
                const float wq[4] = {wv.x, wv.y, wv.z, wv.w};
#pragma unroll
                for (int a = 0; a < 4; ++a)
#pragma unroll
                    for (int q = 0; q < 4; ++q)
                        acc_dn[a][b * 4 + q] += ha[a] * wq[q];
            }
        }
        __syncthreads();
    }
#pragma unroll
    for (int a = 0; a < 4; ++a) {
        const int   t  = ts_s[tg * 4 + a];
        const float wg = wg_s[tg * 4 + a];
        float* ot = out + (size_t)t * D_EMBD + colh * 512 + cg * 4;
#pragma unroll
        for (int b = 0; b < 4; ++b)
#pragma unroll
            for (int q = 0; q < 4; ++q)
                atomicAdd(&ot[b * 128 + q], wg * acc_dn[a][b * 4 + q]);
    }
}

extern "C" void kernel_launch(void* const* d_in, const int* in_sizes, int n_in,
                              void* d_out, int out_size, void* d_ws, size_t ws_size,
                              hipStream_t stream) {
    const float* x  = (const float*)d_in[0];
    const float* rw = (const float*)d_in[1];
    const float* w1 = (const float*)d_in[2];
    const float* w2 = (const float*)d_in[3];
    float* out = (float*)d_out;

    char* ws = (char*)d_ws;
    int*   cnt  = (int*)ws;                 // 8 counters, 128B apart
    int*   tokl = (int*)(ws + WS_TOK);
    float* wgtl = (float*)(ws + WS_WGT);

    hipMemsetAsync(d_ws, 0, 1024, stream);
    hipMemsetAsync(d_out, 0, (size_t)out_size * sizeof(float), stream);

    router2_kernel<<<T_TOKENS / 32, 256, 0, stream>>>(x, rw, cnt, tokl, wgtl);

    if (ws_size >= WS_END) {
        __hip_bfloat16* xb  = (__hip_bfloat16*)(ws + WS_XB);
        __hip_bfloat16* w1b = (__hip_bfloat16*)(ws + WS_W1B);
        __hip_bfloat16* w2b = (__hip_bfloat16*)(ws + WS_W2B);
        __hip_bfloat16* H   = (__hip_bfloat16*)(ws + WS_H);

        convx_kernel<<<T_TOKENS * D_EMBD / 1024, 256, 0, stream>>>(x, xb);
        transpose_bf16_kernel<<<(D_EMBD/64)*(TOTAL_W/64), 256, 0, stream>>>(w1, w1b, D_EMBD, TOTAL_W);
        transpose_bf16_kernel<<<(TOTAL_W/64)*(D_EMBD/64), 256, 0, stream>>>(w2, w2b, TOTAL_W, D_EMBD);

        gemm1_kernel<<<3072, 256, 0, stream>>>((const char*)xb, (const char*)w1b, cnt, tokl, H);
        gemm2_kernel<<<2048, 256, 0, stream>>>((const char*)H, (const char*)w2b, cnt, tokl, wgtl, out);
    } else {
        moe_group_kernel<<<1024 + 2048, 256, 0, stream>>>(x, w1, w2, cnt, tokl, wgtl, out);
    }
}